// Round 1
// 108.658 us; speedup vs baseline: 1.0314x; 1.0314x over previous
//
#include <hip/hip_runtime.h>
#include <math.h>

#define S_DIM 256
#define B_DIM 16
#define F_DIM 200
#define H_DIM 100
#define ROWS (S_DIM * B_DIM)  // 4096

// ---------------------------------------------------------------------------
// K1: Eq = exp(2*(x@Wq)), Ek = exp(2*(x@Wk + b)) per row r = s*B+b.
// 8 rows/block, 256 threads = 2 f-halves x 128 h-lanes. x rows via uniform
// s_loads; W via coalesced vector loads. (unchanged — not in top-5)
// ---------------------------------------------------------------------------
__global__ __launch_bounds__(256) void k1_proj_exp(
    const float* __restrict__ input, const float* __restrict__ Wq,
    const float* __restrict__ Wk, const float* __restrict__ bias,
    float* __restrict__ Eq, float* __restrict__ Ek)
{
    __shared__ float pq[8][128], pk[8][128];
    const int tid = threadIdx.x;
    const int h = tid & 127;
    const int fg = tid >> 7;
    const int hh = (h < H_DIM) ? h : (H_DIM - 1);
    const int r0 = blockIdx.x * 8;
    float accq[8], acck[8];
#pragma unroll
    for (int r = 0; r < 8; ++r) { accq[r] = 0.f; acck[r] = 0.f; }
    const int fb = fg * 100;
    for (int f4 = 0; f4 < 25; ++f4) {
        const int f = fb + f4 * 4;
        const float wq0 = Wq[(f + 0) * H_DIM + hh];
        const float wq1 = Wq[(f + 1) * H_DIM + hh];
        const float wq2 = Wq[(f + 2) * H_DIM + hh];
        const float wq3 = Wq[(f + 3) * H_DIM + hh];
        const float wk0 = Wk[(f + 0) * H_DIM + hh];
        const float wk1 = Wk[(f + 1) * H_DIM + hh];
        const float wk2 = Wk[(f + 2) * H_DIM + hh];
        const float wk3 = Wk[(f + 3) * H_DIM + hh];
#pragma unroll
        for (int r = 0; r < 8; ++r) {
            const float4 xv = *(const float4*)&input[(r0 + r) * F_DIM + f];
            accq[r] = fmaf(xv.x, wq0, accq[r]);
            accq[r] = fmaf(xv.y, wq1, accq[r]);
            accq[r] = fmaf(xv.z, wq2, accq[r]);
            accq[r] = fmaf(xv.w, wq3, accq[r]);
            acck[r] = fmaf(xv.x, wk0, acck[r]);
            acck[r] = fmaf(xv.y, wk1, acck[r]);
            acck[r] = fmaf(xv.z, wk2, acck[r]);
            acck[r] = fmaf(xv.w, wk3, acck[r]);
        }
    }
    if (fg) {
#pragma unroll
        for (int r = 0; r < 8; ++r) { pq[r][h] = accq[r]; pk[r][h] = acck[r]; }
    }
    __syncthreads();
    if (!fg && h < H_DIM) {
        const float bv = bias[h];
#pragma unroll
        for (int r = 0; r < 8; ++r) {
            const float q = accq[r] + pq[r][h];
            const float k = acck[r] + pk[r][h] + bv;
            Eq[(r0 + r) * H_DIM + h] = __expf(2.f * q);
            Ek[(r0 + r) * H_DIM + h] = __expf(2.f * k);
        }
    }
}

// ---------------------------------------------------------------------------
// K2: scores. 2-way fused denominators (6 VALU + 1 rcp per 2 h). Epilogue
// transposes the 64s x 8t tile through LDS (pt[64][9], conflict-free) and
// stores p in [b][s][t] layout so K3's s-loop reads are lane-coalesced.
// (unchanged this round — isolating the K3 delta)
// ---------------------------------------------------------------------------
__global__ __launch_bounds__(256) void k2_scores(
    const float* __restrict__ Eq, const float* __restrict__ Ek,
    const float* __restrict__ vvec, const int* __restrict__ seqlen,
    float* __restrict__ p)
{
    __shared__ float4 klds[64 * 27];
    __shared__ float pt[64][9];
    const int tid = threadIdx.x;
    const int b = blockIdx.z;
    const int len = seqlen[b];
    const int s0 = blockIdx.y * 64;
    const int t0 = blockIdx.x * 8;
    if (s0 >= len || t0 >= len) return;  // block-uniform, before any barrier
    const float4* Ek4 = (const float4*)Ek;
    for (int idx = tid; idx < 64 * 25; idx += 256) {
        int r = idx / 25, c = idx - r * 25;
        klds[r * 27 + c] = Ek4[((s0 + r) * B_DIM + b) * 25 + c];
    }
    __syncthreads();
    const int s = tid & 63;
    const int th = tid >> 6;
    const int tbase = t0 + th * 2;  // <= 255 always

    float sv = 0.f;
    for (int h4 = 0; h4 < 25; ++h4) {
        const float4 vv = *(const float4*)&vvec[h4 * 4];
        sv += (vv.x + vv.y) + (vv.z + vv.w);
    }
    float acc0 = sv, acc1 = sv;
    const float* eq0 = Eq + ((tbase + 0) * B_DIM + b) * H_DIM;
    const float* eq1 = Eq + ((tbase + 1) * B_DIM + b) * H_DIM;
    for (int h4 = 0; h4 < 25; ++h4) {
        const float4 kk = klds[s * 27 + h4];
        const float4 vv = *(const float4*)&vvec[h4 * 4];
        const float4 q0 = *(const float4*)(eq0 + h4 * 4);
        const float4 q1 = *(const float4*)(eq1 + h4 * 4);
        const float vmx = -2.f * vv.x, vmy = -2.f * vv.y;
        const float vmz = -2.f * vv.z, vmw = -2.f * vv.w;
        {
            float dx = fmaf(q0.x, kk.x, 1.f), dy = fmaf(q0.y, kk.y, 1.f);
            float N = fmaf(vmx, dy, vmy * dx);
            acc0 = fmaf(N, __builtin_amdgcn_rcpf(dx * dy), acc0);
            float dz = fmaf(q0.z, kk.z, 1.f), dw = fmaf(q0.w, kk.w, 1.f);
            float M = fmaf(vmz, dw, vmw * dz);
            acc0 = fmaf(M, __builtin_amdgcn_rcpf(dz * dw), acc0);
        }
        {
            float dx = fmaf(q1.x, kk.x, 1.f), dy = fmaf(q1.y, kk.y, 1.f);
            float N = fmaf(vmx, dy, vmy * dx);
            acc1 = fmaf(N, __builtin_amdgcn_rcpf(dx * dy), acc1);
            float dz = fmaf(q1.z, kk.z, 1.f), dw = fmaf(q1.w, kk.w, 1.f);
            float M = fmaf(vmz, dw, vmw * dz);
            acc1 = fmaf(M, __builtin_amdgcn_rcpf(dz * dw), acc1);
        }
    }
    // stage tile in LDS (pad 9 -> conflict-free), then coalesced-ish
    // transposed store: p[b][s0+sr][t0+tr]
    pt[s][th * 2 + 0] = __expf(acc0);
    pt[s][th * 2 + 1] = __expf(acc1);
    __syncthreads();
    float* pb = p + (b * S_DIM + s0) * S_DIM + t0;
#pragma unroll
    for (int v = tid; v < 512; v += 256) {
        const int sr = v >> 3, tr = v & 7;
        if (s0 + sr < len) pb[sr * S_DIM + tr] = pt[sr][tr];
    }
}

// ---------------------------------------------------------------------------
// K3 v2: attended + normalize + full pool. NEW: 1024 threads = 4 s-quarters
// x 256 t-lanes. Each quarter walks s = sq, sq+4, ... (load-balanced for any
// len); the serial s-chain of v1 (the latency tail: len=256 blocks ran 256
// dependent-load steps at 1 wave/SIMD) is cut 4x and hidden by 16 waves/block.
// Partials combined via LDS cacc[3][256][9] (stride 9 -> conflict-free),
// then the sq=0 quarter runs the unchanged normalize+pool epilogue.
// Grid 25 x 16 = 400 blocks, ~39 KB LDS.
// ---------------------------------------------------------------------------
#define K3_BODY(ss) { \
        const float pv = pb[(ss) * S_DIM]; \
        const float4 xa = xlds4[(ss) * 2]; \
        const float4 xb = xlds4[(ss) * 2 + 1]; \
        psum += pv; \
        acc[0] = fmaf(pv, xa.x, acc[0]); \
        acc[1] = fmaf(pv, xa.y, acc[1]); \
        acc[2] = fmaf(pv, xa.z, acc[2]); \
        acc[3] = fmaf(pv, xa.w, acc[3]); \
        acc[4] = fmaf(pv, xb.x, acc[4]); \
        acc[5] = fmaf(pv, xb.y, acc[5]); \
        acc[6] = fmaf(pv, xb.z, acc[6]); \
        acc[7] = fmaf(pv, xb.w, acc[7]); }

__global__ __launch_bounds__(1024) void k3_attend_pool(
    const float* __restrict__ p, const float* __restrict__ input,
    const int* __restrict__ seqlen, float* __restrict__ out)
{
    __shared__ float4 xlds4[512];       // [s][2] : x[s][b][f0..f0+7]
    __shared__ float cacc[3][256][9];   // partial acc from sq=1..3, pad 9
    __shared__ float cps[3][256];       // partial psum from sq=1..3
    __shared__ float lm[4][8], ls[4][8];
    const int tid = threadIdx.x;
    const int t = tid & 255;
    const int sq = tid >> 8;            // s-quarter 0..3
    const int b = blockIdx.y;
    const int len = seqlen[b];
    const int base = b * 50 + blockIdx.x * 2;  // float4 index of x[s=0][b][f0]
    const float4* in4 = (const float4*)input;
    if (tid < 512) {
        const int s = tid >> 1, half = tid & 1;
        xlds4[tid] = in4[s * (B_DIM * 50) + base + half];
    }
    __syncthreads();

    float acc[8];
#pragma unroll
    for (int j = 0; j < 8; ++j) acc[j] = 0.f;
    float psum = 0.f;
    const float* pb = p + b * (S_DIM * S_DIM) + t;  // + s*256

    int s = sq;
    for (; s + 12 < len; s += 16) {     // 4 strided steps in flight
        K3_BODY(s); K3_BODY(s + 4); K3_BODY(s + 8); K3_BODY(s + 12);
    }
    for (; s < len; s += 4) K3_BODY(s);

    if (sq) {
#pragma unroll
        for (int j = 0; j < 8; ++j) cacc[sq - 1][t][j] = acc[j];
        cps[sq - 1][t] = psum;
    }
    __syncthreads();

    if (!sq) {
#pragma unroll
        for (int g = 0; g < 3; ++g) {
            psum += cps[g][t];
#pragma unroll
            for (int j = 0; j < 8; ++j) acc[j] += cacc[g][t][j];
        }
        // normalize + pool over t (lane dimension); tid==t here (tid<256)
        const float rp = __builtin_amdgcn_rcpf(psum);
        const bool ok = (t < len);
        const int w = tid >> 6, lane = tid & 63;
#pragma unroll
        for (int j = 0; j < 8; ++j) {
            const float a = acc[j] * rp;
            float m = ok ? a : -INFINITY;
            float s2 = ok ? a : 0.f;
            for (int off = 32; off; off >>= 1) {
                m = fmaxf(m, __shfl_xor(m, off));
                s2 += __shfl_xor(s2, off);
            }
            if (lane == 0) { lm[w][j] = m; ls[w][j] = s2; }
        }
    }
    __syncthreads();
    if (tid < 8) {
        float m = lm[0][tid], s2 = ls[0][tid];
#pragma unroll
        for (int g = 1; g < 4; ++g) { m = fmaxf(m, lm[g][tid]); s2 += ls[g][tid]; }
        const int f0 = blockIdx.x * 8;
        out[b * (2 * F_DIM) + f0 + tid] = m;
        out[b * (2 * F_DIM) + F_DIM + f0 + tid] = s2 / (float)len;
    }
}

extern "C" void kernel_launch(void* const* d_in, const int* in_sizes, int n_in,
                              void* d_out, int out_size, void* d_ws, size_t ws_size,
                              hipStream_t stream)
{
    const float* input  = (const float*)d_in[0];
    const int*   seqlen = (const int*)d_in[1];
    const float* Wq     = (const float*)d_in[2];
    const float* Wk     = (const float*)d_in[3];
    const float* bias   = (const float*)d_in[4];
    const float* vvec   = (const float*)d_in[5];
    float* out = (float*)d_out;

    float* ws = (float*)d_ws;
    float* Eq = ws;                 // 409600 floats
    float* Ek = ws + 409600;        // 409600 floats
    float* p  = ws + 819200;        // 1048576 floats, layout [b][s][t]

    k1_proj_exp<<<ROWS / 8, 256, 0, stream>>>(input, Wq, Wk, bias, Eq, Ek);
    k2_scores<<<dim3(S_DIM / 8, S_DIM / 64, B_DIM), 256, 0, stream>>>(Eq, Ek, vvec, seqlen, p);
    k3_attend_pool<<<dim3(F_DIM / 8, B_DIM), 1024, 0, stream>>>(p, input, seqlen, out);
}